// Round 7
// baseline (237.188 us; speedup 1.0000x reference)
//
#include <hip/hip_runtime.h>
#include <math.h>

#define FIN 128
#define W 512          // nodes per coarse group
#define S 16           // sub-blocks per group for partial accumulation
#define MAXG 256       // LDS counter capacity (need G=196)
#define CAP 18432u     // per-group packed capacity (mean 16327, sigma~127: 16 sigma)
#define HB 256         // fused scatter blocks
#define HT 1024        // fused scatter threads per block
#define BP 200         // radix table padded stride (>= B=196, mult of 4)

// ---------------------------------------------------------------------------
// helpers
// ---------------------------------------------------------------------------
__device__ __forceinline__ long long edge_at(const void* p, long long i, unsigned mode) {
  return mode ? ((const long long*)p)[i] : (long long)((const int*)p)[i];
}

__device__ __forceinline__ void atomic_fadd(float* p, float v) {
  __hip_atomic_fetch_add(p, v, __ATOMIC_RELAXED, __HIP_MEMORY_SCOPE_AGENT);
}

// ---------------------------------------------------------------------------
// dtype detection + init group cursors (cur[g] = g*CAP) + zero acc
// ---------------------------------------------------------------------------
__global__ void k_detect(const unsigned* ei, unsigned* mode, float* acc,
                         unsigned* cur, int G) {
  int t = threadIdx.x;
  if (t == 0) {
    unsigned orv = 0;
    for (int i = 1; i < 1024; i += 2) orv |= ei[i];
    *mode = (orv == 0) ? 1u : 0u;
    *acc = 0.0f;
  }
  for (int i = t; i < G; i += 64) cur[i] = (unsigned)i * CAP;
}

// ---------------------------------------------------------------------------
// h = x @ conv_w   (32 threads per node, float4 loads)
// ---------------------------------------------------------------------------
__global__ void k_h(const float* __restrict__ x, const float* __restrict__ cw,
                    float* __restrict__ h, int n) {
  int gt = blockIdx.x * blockDim.x + threadIdx.x;
  int node = gt >> 5;
  int sub = gt & 31;
  if (node >= n) return;
  float4 xv = ((const float4*)x)[node * 32 + sub];
  float s0 = xv.x * cw[sub * 8 + 0] + xv.y * cw[sub * 8 + 2] +
             xv.z * cw[sub * 8 + 4] + xv.w * cw[sub * 8 + 6];
  float s1 = xv.x * cw[sub * 8 + 1] + xv.y * cw[sub * 8 + 3] +
             xv.z * cw[sub * 8 + 5] + xv.w * cw[sub * 8 + 7];
  for (int off = 16; off > 0; off >>= 1) {
    s0 += __shfl_down(s0, off, 32);
    s1 += __shfl_down(s1, off, 32);
  }
  if (sub == 0) { h[node * 2] = s0; h[node * 2 + 1] = s1; }
}

// ---------------------------------------------------------------------------
// fused count + reserve + scatter (intra-group order is non-semantic: the
// downstream accumulation is atomic float adds in arbitrary order anyway)
// ---------------------------------------------------------------------------
__global__ void k_scatter2(const void* ei, const float* __restrict__ attr,
                           long long E, int G, unsigned* cur,
                           uint2* __restrict__ packed,
                           const unsigned* __restrict__ mode) {
  __shared__ unsigned hist[MAXG];
  __shared__ unsigned base[MAXG];
  unsigned m = *mode;
  int t = threadIdx.x;
  if (t < MAXG) hist[t] = 0;
  __syncthreads();
  long long perB = (E + HB - 1) / HB;
  long long b0 = (long long)blockIdx.x * perB;
  long long lim = b0 + perB; if (lim > E) lim = E;
  // phase A: count this slice's cols (col data becomes L2-hot for phase C)
  for (long long e = b0 + t; e < lim; e += HT) {
    int c = (int)edge_at(ei, E + e, m);
    atomicAdd(&hist[c >> 9], 1u);
  }
  __syncthreads();
  // phase B: one global reservation per (group, block)
  if (t < G) base[t] = atomicAdd(&cur[t], hist[t]);
  __syncthreads();
  // phase C: scatter
  for (long long e = b0 + t; e < lim; e += HT) {
    int r = (int)edge_at(ei, e, m);
    int c = (int)edge_at(ei, E + e, m);
    float a = attr[e];
    unsigned pos = atomicAdd(&base[c >> 9], 1u);
    packed[pos] = make_uint2(((unsigned)r << 9) | ((unsigned)c & 511u), __float_as_uint(a));
  }
}

// ---------------------------------------------------------------------------
// S-split partial degree, 4-way unrolled (independent loads for MLP)
// ---------------------------------------------------------------------------
__global__ void k_pdeg(const uint2* __restrict__ packed, const unsigned* __restrict__ cur,
                       float* __restrict__ pdeg) {
  __shared__ float sdeg[W];
  int blk = blockIdx.x, t = threadIdx.x;       // 256 threads
  int g = blk >> 4, s = blk & (S - 1);
  sdeg[t] = 0.f; sdeg[t + 256] = 0.f;
  __syncthreads();
  unsigned lo = (unsigned)g * CAP, hi = cur[g];
  unsigned len = hi - lo;
  unsigned per = (len + S - 1) / S;
  unsigned mylo = lo + s * per;
  unsigned myhi = mylo + per; if (myhi > hi) myhi = hi;
  for (unsigned b = mylo + t; b < myhi; b += 4 * 256) {
    unsigned k0 = b, k1 = b + 256, k2 = b + 512, k3 = b + 768;
    uint2 p0 = packed[k0];
    uint2 p1 = packed[k1 < myhi ? k1 : b];
    uint2 p2 = packed[k2 < myhi ? k2 : b];
    uint2 p3 = packed[k3 < myhi ? k3 : b];
    atomicAdd(&sdeg[p0.x & (W - 1u)], __uint_as_float(p0.y));
    if (k1 < myhi) atomicAdd(&sdeg[p1.x & (W - 1u)], __uint_as_float(p1.y));
    if (k2 < myhi) atomicAdd(&sdeg[p2.x & (W - 1u)], __uint_as_float(p2.y));
    if (k3 < myhi) atomicAdd(&sdeg[p3.x & (W - 1u)], __uint_as_float(p3.y));
  }
  __syncthreads();
  pdeg[(size_t)blk * W + t] = sdeg[t];
  pdeg[(size_t)blk * W + t + 256] = sdeg[t + 256];
}

// reduce partials: dinv = rsqrt(1 + sum_s pdeg); g[r] = dinv[r]*h[r]
__global__ void k_dinv(const float* __restrict__ pdeg, const float* __restrict__ h,
                       float* __restrict__ dinv, float* __restrict__ g, int n) {
  int i = blockIdx.x * blockDim.x + threadIdx.x;
  if (i >= n) return;
  int grp = i >> 9, li = i & (W - 1);
  float d = 1.0f;
#pragma unroll
  for (int s = 0; s < S; ++s) d += pdeg[((size_t)(grp * S + s)) * W + li];
  float di = rsqrtf(d);
  dinv[i] = di;
  g[2 * i]     = di * h[2 * i];
  g[2 * i + 1] = di * h[2 * i + 1];
}

// S-split partial messages, 4-way unrolled (4 independent packed->gather chains)
__global__ void k_pmsg(const uint2* __restrict__ packed, const unsigned* __restrict__ cur,
                       const float* __restrict__ gv, float* __restrict__ pacc) {
  __shared__ float sacc[2 * W];
  int blk = blockIdx.x, t = threadIdx.x;       // 256 threads
  int g = blk >> 4, s = blk & (S - 1);
#pragma unroll
  for (int i = 0; i < 4; ++i) sacc[t + 256 * i] = 0.f;
  __syncthreads();
  unsigned lo = (unsigned)g * CAP, hi = cur[g];
  unsigned len = hi - lo;
  unsigned per = (len + S - 1) / S;
  unsigned mylo = lo + s * per;
  unsigned myhi = mylo + per; if (myhi > hi) myhi = hi;
  const float2* g2 = (const float2*)gv;
  for (unsigned b = mylo + t; b < myhi; b += 4 * 256) {
    unsigned k1 = b + 256, k2 = b + 512, k3 = b + 768;
    uint2 p0 = packed[b];
    uint2 p1 = packed[k1 < myhi ? k1 : b];
    uint2 p2 = packed[k2 < myhi ? k2 : b];
    uint2 p3 = packed[k3 < myhi ? k3 : b];
    float2 g0 = g2[p0.x >> 9];
    float2 g1 = g2[p1.x >> 9];
    float2 g2v = g2[p2.x >> 9];
    float2 g3 = g2[p3.x >> 9];
    float a0 = __uint_as_float(p0.y), a1 = __uint_as_float(p1.y);
    float a2 = __uint_as_float(p2.y), a3 = __uint_as_float(p3.y);
    unsigned c0 = p0.x & (W - 1u), c1 = p1.x & (W - 1u);
    unsigned c2 = p2.x & (W - 1u), c3 = p3.x & (W - 1u);
    atomicAdd(&sacc[2 * c0],     a0 * g0.x);
    atomicAdd(&sacc[2 * c0 + 1], a0 * g0.y);
    if (k1 < myhi) { atomicAdd(&sacc[2 * c1], a1 * g1.x); atomicAdd(&sacc[2 * c1 + 1], a1 * g1.y); }
    if (k2 < myhi) { atomicAdd(&sacc[2 * c2], a2 * g2v.x); atomicAdd(&sacc[2 * c2 + 1], a2 * g2v.y); }
    if (k3 < myhi) { atomicAdd(&sacc[2 * c3], a3 * g3.x); atomicAdd(&sacc[2 * c3 + 1], a3 * g3.y); }
  }
  __syncthreads();
#pragma unroll
  for (int i = 0; i < 4; ++i) pacc[(size_t)blk * (2 * W) + t + 256 * i] = sacc[t + 256 * i];
}

// ---------------------------------------------------------------------------
// reduce message partials + ReLU + score + sort keys + pass-0 radix histogram
// (block g covers nodes [512g, 512g+512) == radix chunk g exactly)
// ---------------------------------------------------------------------------
__global__ void k_gout(const float* __restrict__ pacc, const float* __restrict__ dinv,
                       const float* __restrict__ h, const float* __restrict__ cb,
                       const float* __restrict__ pw, float* __restrict__ out,
                       float* __restrict__ score, unsigned* __restrict__ keys,
                       unsigned* __restrict__ pay, unsigned* __restrict__ table, int n) {
  __shared__ unsigned hist[256];
  int g = blockIdx.x, t = threadIdx.x;         // 512 threads
  if (t < 256) hist[t] = 0;
  __syncthreads();
  const float2* p2 = (const float2*)pacc;
  float a0 = 0.f, a1 = 0.f;
#pragma unroll
  for (int s = 0; s < S; ++s) {
    float2 v = p2[(size_t)(g * S + s) * W + t];
    a0 += v.x; a1 += v.y;
  }
  int c = g * W + t;
  if (c < n) {
    float dc = dinv[c];
    float o0 = fmaxf(dc * a0 + dc * dc * h[2 * c]     + cb[0], 0.f);
    float o1 = fmaxf(dc * a1 + dc * dc * h[2 * c + 1] + cb[1], 0.f);
    out[2 * c] = o0; out[2 * c + 1] = o1;
    float pw0 = pw[0], pw1 = pw[1];
    float s = tanhf((o0 * pw0 + o1 * pw1) / sqrtf(pw0 * pw0 + pw1 * pw1));
    score[c] = s;
    unsigned u = __float_as_uint(s);
    unsigned asc = u ^ ((u >> 31) ? 0xFFFFFFFFu : 0x80000000u);
    unsigned key = ~asc;       // descending-order key, sort ascending
    keys[c] = key;
    pay[c] = (unsigned)c;
    atomicAdd(&hist[key & 255u], 1u);
  }
  __syncthreads();
  if (t < 256) table[t * BP + g] = hist[t];
}

// ---------------------------------------------------------------------------
// stable LSD radix sort, 4 x 8-bit passes, chunk=512, 512-thread blocks
// ---------------------------------------------------------------------------
__global__ void k_rhist(const unsigned* __restrict__ keys, int n, int shift,
                        unsigned* table) {
  __shared__ unsigned hist[256];
  int t = threadIdx.x;
  if (t < 256) hist[t] = 0;
  __syncthreads();
  int g = blockIdx.x * 512 + t;
  if (g < n) atomicAdd(&hist[(keys[g] >> shift) & 255u], 1u);
  __syncthreads();
  if (t < 256) table[t * BP + blockIdx.x] = hist[t];
}

// parallel exclusive scan over digit-major table (256 rows x B entries)
__global__ void k_rscan(unsigned* table, int B) {
  int t = threadIdx.x;                    // 256 threads, one digit row each
  unsigned* row = table + t * BP;
  uint4* r4 = (uint4*)row;
  int nv = B >> 2;
  unsigned s = 0;
#pragma unroll 8
  for (int i = 0; i < nv; ++i) { uint4 v = r4[i]; s += v.x + v.y + v.z + v.w; }
  for (int i = nv * 4; i < B; ++i) s += row[i];
  int lane = t & 63, w = t >> 6;
  unsigned inc = s;
  for (int off = 1; off < 64; off <<= 1) {
    unsigned nval = __shfl_up(inc, off);
    if (lane >= off) inc += nval;
  }
  __shared__ unsigned wtot[4];
  if (lane == 63) wtot[w] = inc;
  __syncthreads();
  unsigned wpre = 0;
  for (int i = 0; i < w; ++i) wpre += wtot[i];
  unsigned run = wpre + inc - s;          // exclusive prefix of this row
#pragma unroll 8
  for (int i = 0; i < nv; ++i) {
    uint4 v = r4[i]; uint4 o;
    o.x = run; run += v.x; o.y = run; run += v.y;
    o.z = run; run += v.z; o.w = run; run += v.w;
    r4[i] = o;
  }
  for (int i = nv * 4; i < B; ++i) { unsigned v = row[i]; row[i] = run; run += v; }
}

__global__ void k_rscatter(const unsigned* __restrict__ keysIn,
                           const unsigned* __restrict__ payIn, int n, int shift,
                           const unsigned* __restrict__ table,
                           unsigned* keysOut, unsigned* payOut) {
  __shared__ unsigned waveCnt[8 * 256];
  int t = threadIdx.x;                     // 512 threads = 8 waves
  int lane = t & 63, w = t >> 6;
  for (int q = t; q < 8 * 256; q += 512) waveCnt[q] = 0;
  __syncthreads();
  int g = blockIdx.x * 512 + t;
  bool active = g < n;
  unsigned key = 0, pay = 0, d = 0;
  if (active) { key = keysIn[g]; pay = payIn[g]; d = (key >> shift) & 255u; }
  unsigned long long am = __ballot(active);
  unsigned long long mm = ~0ull;
#pragma unroll
  for (int b = 0; b < 8; ++b) {
    unsigned long long bb = __ballot((d >> b) & 1u);
    mm &= ((d >> b) & 1u) ? bb : ~bb;
  }
  mm &= am;
  int rankw = __popcll(mm & ((1ull << lane) - 1ull));
  if (active && rankw == 0) waveCnt[w * 256 + d] = (unsigned)__popcll(mm);
  __syncthreads();
  if (active) {
    unsigned off = (unsigned)rankw;
    for (int ww = 0; ww < w; ++ww) off += waveCnt[ww * 256 + d];
    unsigned gpos = table[d * BP + blockIdx.x] + off;
    keysOut[gpos] = key;
    payOut[gpos] = pay;
  }
}

// ---------------------------------------------------------------------------
// y-pre = sum_j score[perm[j]] * (out[perm[j]] . fc_w[2j:2j+2])
// ---------------------------------------------------------------------------
__global__ void k_final(const unsigned* __restrict__ perm, const float* __restrict__ out,
                        const float* __restrict__ score, const float* __restrict__ fcw,
                        float* acc, int n) {
  int stride = gridDim.x * blockDim.x;
  float s = 0.f;
  const float2* o2 = (const float2*)out;
  const float2* f2 = (const float2*)fcw;
  for (int j = blockIdx.x * blockDim.x + threadIdx.x; j < n; j += stride) {
    unsigned p = perm[j];
    float2 ov = o2[p];
    float2 fv = f2[j];
    s += score[p] * (ov.x * fv.x + ov.y * fv.y);
  }
  for (int off = 32; off > 0; off >>= 1) s += __shfl_down(s, off);
  if ((threadIdx.x & 63) == 0) atomic_fadd(acc, s);
}

__global__ void k_sigmoid(const float* acc, const float* __restrict__ fcb, float* y) {
  if (threadIdx.x == 0 && blockIdx.x == 0) {
    float z = *acc + fcb[0];
    y[0] = 1.f / (1.f + expf(-z));
  }
}

// ---------------------------------------------------------------------------
extern "C" void kernel_launch(void* const* d_in, const int* in_sizes, int n_in,
                              void* d_out, int out_size, void* d_ws, size_t ws_size,
                              hipStream_t stream) {
  const float* x     = (const float*)d_in[0];
  const void*  ei    = d_in[1];
  const float* attr  = (const float*)d_in[2];
  const float* convw = (const float*)d_in[3];
  const float* convb = (const float*)d_in[4];
  const float* poolw = (const float*)d_in[5];
  const float* fcw   = (const float*)d_in[6];
  const float* fcb   = (const float*)d_in[7];
  float* y = (float*)d_out;

  int N = in_sizes[0] / FIN;      // 100000
  long long E = in_sizes[2];      // 3200000
  int B = (N + 511) / 512;        // radix chunks (196)
  int G = (N + W - 1) / W;        // 196 coarse groups

  // workspace carve (4-byte units; 8B alignment for uint2/float2 arrays)
  float* ws = (float*)d_ws;
  size_t off = 0;
  uint2* packed  = (uint2*)(ws + off); off += (size_t)2 * G * CAP;
  // pdeg aliases the low half of pacc (pdeg consumed by k_dinv before k_pmsg)
  float* pacc    = ws + off; off += (size_t)2 * G * S * W;
  float* pdeg    = pacc;
  float* h       = ws + off; off += (size_t)2 * N;
  float* dinv    = ws + off; off += (size_t)N;
  float* gv      = ws + off; off += (size_t)2 * N;
  float* outN    = ws + off; off += (size_t)2 * N;
  float* score   = ws + off; off += (size_t)N;
  unsigned* keysA = (unsigned*)(ws + off); off += (size_t)N;
  unsigned* payA  = (unsigned*)(ws + off); off += (size_t)N;
  unsigned* keysB = (unsigned*)(ws + off); off += (size_t)N;
  unsigned* payB  = (unsigned*)(ws + off); off += (size_t)N;
  unsigned* cur   = (unsigned*)(ws + off); off += (size_t)G;
  unsigned* stab  = (unsigned*)(ws + off); off += (size_t)256 * BP;
  float* acc      = ws + off; off += 1;
  unsigned* mode  = (unsigned*)(ws + off); off += 1;

  int nb = (N + 255) / 256;

  k_detect<<<1, 64, 0, stream>>>((const unsigned*)ei, mode, acc, cur, G);
  k_h<<<(N * 32 + 255) / 256, 256, 0, stream>>>(x, convw, h, N);

  // ---- fused edge bucketing ----
  k_scatter2<<<HB, HT, 0, stream>>>(ei, attr, E, G, cur, packed, mode);

  // ---- GCN conv via S-split grouped accumulation ----
  k_pdeg<<<G * S, 256, 0, stream>>>(packed, cur, pdeg);
  k_dinv<<<nb, 256, 0, stream>>>(pdeg, h, dinv, gv, N);
  k_pmsg<<<G * S, 256, 0, stream>>>(packed, cur, gv, pacc);
  k_gout<<<G, W, 0, stream>>>(pacc, dinv, h, convb, poolw, outN, score,
                              keysA, payA, stab, N);

  // ---- 4 stable radix passes: A->B->A->B->A (pass-0 hist fused in k_gout) ----
  unsigned* ki = keysA; unsigned* pi = payA;
  unsigned* ko = keysB; unsigned* po = payB;
  for (int p = 0; p < 4; ++p) {
    int shift = 8 * p;
    if (p > 0) k_rhist<<<B, 512, 0, stream>>>(ki, N, shift, stab);
    k_rscan<<<1, 256, 0, stream>>>(stab, B);
    k_rscatter<<<B, 512, 0, stream>>>(ki, pi, N, shift, stab, ko, po);
    unsigned* tk = ki; ki = ko; ko = tk;
    unsigned* tp = pi; pi = po; po = tp;
  }
  // perm now in pi (== payA)

  k_final<<<196, 256, 0, stream>>>(pi, outN, score, fcw, acc, N);
  k_sigmoid<<<1, 64, 0, stream>>>(acc, fcb, y);
}